// Round 1
// baseline (424.638 us; speedup 1.0000x reference)
//
#include <hip/hip_runtime.h>
#include <math.h>

#define BB    4
#define TT    1024
#define DD    512
#define NH    8
#define DH    64
#define BH    32          // BB*NH
#define INV_TAU 10.0f

// ---------------------------------------------------------------------------
// K1: fused QKV projection + per-head softmax(x/tau) over Dh.
// C[M=4096, N=1536] = x[4096,512] @ [wq|wk|wv]. 64x64 tiles, 16x16 threads,
// 4x4 microtile. N-tile (64) == one (tensor, head) group -> fuse softmax.
// Output layout: [B, H, T, Dh].
// ---------------------------------------------------------------------------
__global__ __launch_bounds__(256) void k_proj_softmax(
    const float* __restrict__ x, const float* __restrict__ wq,
    const float* __restrict__ wk, const float* __restrict__ wv,
    float* __restrict__ qs, float* __restrict__ ks, float* __restrict__ vs)
{
  __shared__ float Xs[16][68];
  __shared__ float Ws[16][68];
  const int tx = threadIdx.x, ty = threadIdx.y;
  const int tid = ty * 16 + tx;
  const int n0 = blockIdx.x * 64;          // 0..1535
  const int m0 = blockIdx.y * 64;          // 0..4095
  const int tensor = n0 >> 9;
  const float* Wp = (tensor == 0) ? wq : ((tensor == 1) ? wk : wv);
  float* outp = (tensor == 0) ? qs : ((tensor == 1) ? ks : vs);
  const int nc = n0 & 511;

  const int lm = tid >> 2;                 // 0..63 (X row)
  const int lk = (tid & 3) * 4;            // 0,4,8,12 (X k quad)
  const int wkr = tid >> 4;                // 0..15 (W k row)
  const int wnc = (tid & 15) * 4;          // 0..60 (W n quad)

  float acc[4][4] = {};
  for (int k0 = 0; k0 < DD; k0 += 16) {
    float4 xv = *(const float4*)&x[(size_t)(m0 + lm) * DD + k0 + lk];
    float4 wv4 = *(const float4*)&Wp[(size_t)(k0 + wkr) * DD + nc + wnc];
    Xs[lk + 0][lm] = xv.x; Xs[lk + 1][lm] = xv.y;
    Xs[lk + 2][lm] = xv.z; Xs[lk + 3][lm] = xv.w;
    *(float4*)&Ws[wkr][wnc] = wv4;
    __syncthreads();
#pragma unroll
    for (int kk = 0; kk < 16; ++kk) {
      float4 a4 = *(const float4*)&Xs[kk][ty * 4];
      float4 b4 = *(const float4*)&Ws[kk][tx * 4];
      float a[4] = {a4.x, a4.y, a4.z, a4.w};
      float b[4] = {b4.x, b4.y, b4.z, b4.w};
#pragma unroll
      for (int r = 0; r < 4; ++r)
#pragma unroll
        for (int c = 0; c < 4; ++c) acc[r][c] += a[r] * b[c];
    }
    __syncthreads();
  }

  // Softmax epilogue: rows m0+ty*4+r, 64 cols spread over 16 tx threads.
  const int h = nc >> 6;
  const int bidx = m0 >> 10;               // batch (64 | 1024 so constant/tile)
  const int trow = m0 & 1023;
#pragma unroll
  for (int r = 0; r < 4; ++r) {
    float mx = fmaxf(fmaxf(acc[r][0], acc[r][1]), fmaxf(acc[r][2], acc[r][3]));
#pragma unroll
    for (int msk = 1; msk <= 8; msk <<= 1) mx = fmaxf(mx, __shfl_xor(mx, msk, 64));
    float e0 = __expf((acc[r][0] - mx) * INV_TAU);
    float e1 = __expf((acc[r][1] - mx) * INV_TAU);
    float e2 = __expf((acc[r][2] - mx) * INV_TAU);
    float e3 = __expf((acc[r][3] - mx) * INV_TAU);
    float sm = e0 + e1 + e2 + e3;
#pragma unroll
    for (int msk = 1; msk <= 8; msk <<= 1) sm += __shfl_xor(sm, msk, 64);
    float inv = 1.0f / sm;
    float4 p = make_float4(e0 * inv, e1 * inv, e2 * inv, e3 * inv);
    int t = trow + ty * 4 + r;
    *(float4*)&outp[(((size_t)bidx * NH + h) * TT + t) * DH + tx * 4] = p;
  }
}

// ---------------------------------------------------------------------------
// K2: A[z,i,j] = sum_d q[z,i,d]*k[z,j,d], lower-triangle 64x64 tiles only.
// ---------------------------------------------------------------------------
__global__ __launch_bounds__(256) void k_qk(
    const float* __restrict__ qs, const float* __restrict__ ks,
    float* __restrict__ A)
{
  __shared__ float Qs[16][68];
  __shared__ float Ks[16][68];
  const int z = blockIdx.y;
  const int lx = blockIdx.x;               // 0..135 lower-tri tile id
  int ti = (int)((sqrtf(8.0f * lx + 1.0f) - 1.0f) * 0.5f);
  while ((ti + 1) * (ti + 2) / 2 <= lx) ++ti;
  while (ti * (ti + 1) / 2 > lx) --ti;
  const int tj = lx - ti * (ti + 1) / 2;
  const int i0 = ti * 64, j0 = tj * 64;
  const float* Qb = qs + (size_t)z * TT * DH;
  const float* Kb = ks + (size_t)z * TT * DH;
  const int tx = threadIdx.x, ty = threadIdx.y;
  const int tid = ty * 16 + tx;
  const int lm = tid >> 2, lk = (tid & 3) * 4;

  float acc[4][4] = {};
  for (int k0 = 0; k0 < DH; k0 += 16) {
    float4 qv = *(const float4*)&Qb[(size_t)(i0 + lm) * DH + k0 + lk];
    float4 kv = *(const float4*)&Kb[(size_t)(j0 + lm) * DH + k0 + lk];
    Qs[lk + 0][lm] = qv.x; Qs[lk + 1][lm] = qv.y;
    Qs[lk + 2][lm] = qv.z; Qs[lk + 3][lm] = qv.w;
    Ks[lk + 0][lm] = kv.x; Ks[lk + 1][lm] = kv.y;
    Ks[lk + 2][lm] = kv.z; Ks[lk + 3][lm] = kv.w;
    __syncthreads();
#pragma unroll
    for (int kk = 0; kk < 16; ++kk) {
      float4 a4 = *(const float4*)&Qs[kk][ty * 4];
      float4 b4 = *(const float4*)&Ks[kk][tx * 4];
      float a[4] = {a4.x, a4.y, a4.z, a4.w};
      float b[4] = {b4.x, b4.y, b4.z, b4.w};
#pragma unroll
      for (int r = 0; r < 4; ++r)
#pragma unroll
        for (int c = 0; c < 4; ++c) acc[r][c] += a[r] * b[c];
    }
    __syncthreads();
  }

  float* Ab = A + (size_t)z * TT * TT;
#pragma unroll
  for (int r = 0; r < 4; ++r) {
    const int i = i0 + ty * 4 + r;
    const int jb = j0 + tx * 4;
    if (ti != tj) {
      float4 v = make_float4(acc[r][0], acc[r][1], acc[r][2], acc[r][3]);
      *(float4*)&Ab[(size_t)i * TT + jb] = v;
    } else {
#pragma unroll
      for (int c = 0; c < 4; ++c)
        if (jb + c <= i) Ab[(size_t)i * TT + jb + c] = acc[r][c];
    }
  }
}

// ---------------------------------------------------------------------------
// K3: run-length scan along diagonals, in place.
// For diagonal d: s_i = A[i, i-d]; cs = prefix-sum(s);
// m = prefix-max(cs*(1-s)) (leading zero rows give m init 0); out = cs - m.
// One thread per diagonal; contiguous addresses across lanes at each step.
// ---------------------------------------------------------------------------
__global__ __launch_bounds__(64) void k_scan(float* __restrict__ A)
{
  const int z = blockIdx.y;
  const int dbase = blockIdx.x * 64;
  const int d = dbase + threadIdx.x;
  float* __restrict__ Ab = A + (size_t)z * TT * TT;
  float cs = 0.0f, m = 0.0f;
  for (int i0 = dbase; i0 < TT; i0 += 8) {
    float s[8], o[8];
#pragma unroll
    for (int u = 0; u < 8; ++u) {
      int i = i0 + u;
      s[u] = (i >= d) ? Ab[(size_t)i * TT + (i - d)] : 0.0f;
    }
#pragma unroll
    for (int u = 0; u < 8; ++u) {
      cs += s[u];
      float g = cs * (1.0f - s[u]);
      m = fmaxf(m, g);
      o[u] = cs - m;
    }
#pragma unroll
    for (int u = 0; u < 8; ++u) {
      int i = i0 + u;
      if (i >= d) Ab[(size_t)i * TT + (i - d)] = o[u];
    }
  }
}

// ---------------------------------------------------------------------------
// K4: row softmax (with positional tie-break, /tau). Writes unnormalized
// exp back into A and the row sum to rowsum[].
// ---------------------------------------------------------------------------
__global__ __launch_bounds__(256) void k_rowsoftmax(
    float* __restrict__ A, float* __restrict__ rowsum)
{
  const int row = blockIdx.x;              // 0..BH*TT-1
  const int i = row & (TT - 1);
  const int tid = threadIdx.x;
  float* __restrict__ Ar = A + (size_t)row * TT;
  const float inv_i1 = 1.0f / (float)(i + 1);

  float v[4];
  float mx = -1e30f;
#pragma unroll
  for (int u = 0; u < 4; ++u) {
    int j = u * 256 + tid;
    if (j <= i) {
      v[u] = Ar[j] + (float)j * inv_i1;
      mx = fmaxf(mx, v[u]);
    } else {
      v[u] = -1e30f;
    }
  }
#pragma unroll
  for (int msk = 1; msk <= 32; msk <<= 1) mx = fmaxf(mx, __shfl_xor(mx, msk, 64));
  __shared__ float redm[4];
  __shared__ float reds[4];
  const int wid = tid >> 6, lid = tid & 63;
  if (lid == 0) redm[wid] = mx;
  __syncthreads();
  mx = fmaxf(fmaxf(redm[0], redm[1]), fmaxf(redm[2], redm[3]));

  float sm = 0.0f;
#pragma unroll
  for (int u = 0; u < 4; ++u) {
    int j = u * 256 + tid;
    if (j <= i) {
      float e = __expf((v[u] - mx) * INV_TAU);
      Ar[j] = e;
      sm += e;
    }
  }
#pragma unroll
  for (int msk = 1; msk <= 32; msk <<= 1) sm += __shfl_xor(sm, msk, 64);
  if (lid == 0) reds[wid] = sm;
  __syncthreads();
  if (tid == 0) rowsum[row] = reds[0] + reds[1] + reds[2] + reds[3];
}

// ---------------------------------------------------------------------------
// K5: O[z,i,d] = (sum_{j<=i} P[z,i,j] * V[z,j,d]) / rowsum[z,i]
// ---------------------------------------------------------------------------
__global__ __launch_bounds__(256) void k_pv(
    const float* __restrict__ A, const float* __restrict__ vs,
    const float* __restrict__ rowsum, float* __restrict__ oatt)
{
  __shared__ float Ps[16][68];
  __shared__ float Vs[16][68];
  const int z = blockIdx.y, ti = blockIdx.x;
  const int i0 = ti * 64;
  const float* Ab = A + (size_t)z * TT * TT;
  const float* Vb = vs + (size_t)z * TT * DH;
  const int tx = threadIdx.x, ty = threadIdx.y;
  const int tid = ty * 16 + tx;
  const int lm = tid >> 2, lk = (tid & 3) * 4;   // P loader
  const int vk = tid >> 4, vn = (tid & 15) * 4;  // V loader

  float acc[4][4] = {};
  const int jend = i0 + 64;
  for (int j0 = 0; j0 < jend; j0 += 16) {
    const int irow = i0 + lm;
    const float* src = &Ab[(size_t)irow * TT + j0 + lk];
    float p0 = (j0 + lk + 0 <= irow) ? src[0] : 0.0f;
    float p1 = (j0 + lk + 1 <= irow) ? src[1] : 0.0f;
    float p2 = (j0 + lk + 2 <= irow) ? src[2] : 0.0f;
    float p3 = (j0 + lk + 3 <= irow) ? src[3] : 0.0f;
    Ps[lk + 0][lm] = p0; Ps[lk + 1][lm] = p1;
    Ps[lk + 2][lm] = p2; Ps[lk + 3][lm] = p3;
    *(float4*)&Vs[vk][vn] = *(const float4*)&Vb[(size_t)(j0 + vk) * DH + vn];
    __syncthreads();
#pragma unroll
    for (int kk = 0; kk < 16; ++kk) {
      float4 a4 = *(const float4*)&Ps[kk][ty * 4];
      float4 b4 = *(const float4*)&Vs[kk][tx * 4];
      float a[4] = {a4.x, a4.y, a4.z, a4.w};
      float b[4] = {b4.x, b4.y, b4.z, b4.w};
#pragma unroll
      for (int r = 0; r < 4; ++r)
#pragma unroll
        for (int c = 0; c < 4; ++c) acc[r][c] += a[r] * b[c];
    }
    __syncthreads();
  }

#pragma unroll
  for (int r = 0; r < 4; ++r) {
    const int i = i0 + ty * 4 + r;
    const float inv = 1.0f / rowsum[(size_t)z * TT + i];
    float4 v = make_float4(acc[r][0] * inv, acc[r][1] * inv,
                           acc[r][2] * inv, acc[r][3] * inv);
    *(float4*)&oatt[((size_t)z * TT + i) * DH + tx * 4] = v;
  }
}

// ---------------------------------------------------------------------------
// K6: per-head output projection.
// out[b, t, h*64+e] = sum_d oatt[b,h,t,d] * wo[(h*64+d)*64 + e]
// ---------------------------------------------------------------------------
__global__ __launch_bounds__(256) void k_oproj(
    const float* __restrict__ oatt, const float* __restrict__ wo,
    float* __restrict__ out)
{
  __shared__ float Wl[64][64];
  __shared__ float Ol[4][64];
  const int z = blockIdx.y;                // b*NH + h
  const int t0 = blockIdx.x * 4;
  const int b = z >> 3, h = z & 7;
  const int tid = threadIdx.x;
  const float* wb = wo + (size_t)h * 64 * 64;
#pragma unroll
  for (int u = 0; u < 4; ++u) {
    int q = tid + 256 * u;                 // float4 index 0..1023
    int dd = q >> 4, e4 = (q & 15) * 4;
    *(float4*)&Wl[dd][e4] = *(const float4*)&wb[(size_t)dd * 64 + e4];
  }
  {
    int r = tid >> 6, dd = tid & 63;
    Ol[r][dd] = oatt[((size_t)z * TT + t0 + r) * DH + dd];
  }
  __syncthreads();
  const int r = tid >> 6, e = tid & 63;
  float acc = 0.0f;
#pragma unroll
  for (int d = 0; d < 64; ++d) acc += Ol[r][d] * Wl[d][e];
  out[((size_t)b * TT + t0 + r) * DD + h * 64 + e] = acc;
}

// ---------------------------------------------------------------------------
extern "C" void kernel_launch(void* const* d_in, const int* in_sizes, int n_in,
                              void* d_out, int out_size, void* d_ws, size_t ws_size,
                              hipStream_t stream)
{
  (void)in_sizes; (void)n_in; (void)out_size; (void)ws_size;
  const float* x  = (const float*)d_in[0];
  const float* wq = (const float*)d_in[1];
  const float* wk = (const float*)d_in[2];
  const float* wv = (const float*)d_in[3];
  const float* wo = (const float*)d_in[4];
  float* out = (float*)d_out;

  char* ws = (char*)d_ws;
  float* qs     = (float*)(ws);                                  // 8 MB
  float* ks     = (float*)(ws + (size_t)8  * 1024 * 1024);       // 8 MB
  float* vs     = (float*)(ws + (size_t)16 * 1024 * 1024);       // 8 MB
  float* oatt   = (float*)(ws + (size_t)24 * 1024 * 1024);       // 8 MB
  float* rowsum = (float*)(ws + (size_t)32 * 1024 * 1024);       // 128 KB
  float* A      = (float*)(ws + (size_t)33 * 1024 * 1024);       // 128 MB

  hipLaunchKernelGGL(k_proj_softmax, dim3(24, 64), dim3(16, 16), 0, stream,
                     x, wq, wk, wv, qs, ks, vs);
  hipLaunchKernelGGL(k_qk, dim3(136, BH), dim3(16, 16), 0, stream, qs, ks, A);
  hipLaunchKernelGGL(k_scan, dim3(TT / 64, BH), dim3(64), 0, stream, A);
  hipLaunchKernelGGL(k_rowsoftmax, dim3(BH * TT), dim3(256), 0, stream, A, rowsum);
  hipLaunchKernelGGL(k_pv, dim3(TT / 64, BH), dim3(16, 16), 0, stream,
                     A, vs, rowsum, oatt);
  hipLaunchKernelGGL(k_oproj, dim3(TT / 4, BH), dim3(256), 0, stream,
                     oatt, wo, out);
}